// Round 1
// baseline (474.689 us; speedup 1.0000x reference)
//
#include <hip/hip_runtime.h>
#include <hip/hip_bf16.h>

#define S_LEN  1024
#define BATCH  4
#define DMODEL 1024
#define NHEAD  16
#define DHEAD  64
#define NROWS  (S_LEN*BATCH)   // 4096

typedef __bf16 bf16;
typedef __bf16 bf16x4 __attribute__((ext_vector_type(4)));
typedef __bf16 bf16x8 __attribute__((ext_vector_type(8)));
typedef float  f32x4  __attribute__((ext_vector_type(4)));

// ---------------- fp32 -> bf16 convert ----------------
__global__ __launch_bounds__(256) void cvt_f32_bf16(const float* __restrict__ src,
                                                    bf16* __restrict__ dst, int n8) {
  int i = blockIdx.x * 256 + threadIdx.x;
  if (i >= n8) return;
  const float4* s4 = (const float4*)src;
  float4 a = s4[2*i], b = s4[2*i+1];
  bf16x8 o;
  o[0]=(bf16)a.x; o[1]=(bf16)a.y; o[2]=(bf16)a.z; o[3]=(bf16)a.w;
  o[4]=(bf16)b.x; o[5]=(bf16)b.y; o[6]=(bf16)b.z; o[7]=(bf16)b.w;
  ((bf16x8*)dst)[i] = o;
}

// ---------------- fused QKV GEMM (bf16 MFMA) ----------------
// X: [4096][1024] bf16 (row r = s*B+b), Wcat: [3*1024][1024] bf16 (rows = out features)
// out[r][o] = sum_d X[r][d]*W[o][d] + bias[o];  Q/K/V stored [B][H][S][DH] bf16
#define BM 64
#define BN 64
#define BK 32
#define LDK 40   // padded LDS leading dim (bf16 elems)

__global__ __launch_bounds__(256) void qkv_gemm(
    const bf16* __restrict__ X, const bf16* __restrict__ Wcat,
    const float* __restrict__ bq, const float* __restrict__ bk, const float* __restrict__ bv,
    bf16* __restrict__ Qo, bf16* __restrict__ Ko, bf16* __restrict__ Vo)
{
  __shared__ bf16 Xs[BM][LDK];
  __shared__ bf16 Ws[BN][LDK];

  const int tid  = threadIdx.x;
  const int row0 = blockIdx.x * BM;          // 0..4032
  const int col0 = blockIdx.y * BN;          // 0..3008 (global out-feature)
  const int wsel = col0 >> 10;               // 0=q 1=k 2=v (tile never straddles)
  const int coln = col0 & 1023;

  const int sr = tid >> 2;                   // staging row 0..63
  const int sc = (tid & 3) << 3;             // staging col 0,8,16,24 (bf16)

  const int wv   = tid >> 6;                 // wave 0..3
  const int lane = tid & 63;
  const int wr   = (wv >> 1) << 5;           // wave row offset 0/32
  const int wc   = (wv & 1) << 5;            // wave col offset 0/32
  const int lr   = lane & 15;
  const int kl   = (lane >> 4) << 2;         // k-lane offset 0,4,8,12

  f32x4 acc[2][2];
  #pragma unroll
  for (int mi=0; mi<2; ++mi)
    #pragma unroll
    for (int ni=0; ni<2; ++ni)
      acc[mi][ni] = (f32x4){0.f,0.f,0.f,0.f};

  for (int k0 = 0; k0 < DMODEL; k0 += BK) {
    // stage 64x32 tiles of X and W (each thread: one 16B load/store)
    *(uint4*)&Xs[sr][sc] = *(const uint4*)&X[(size_t)(row0+sr)*DMODEL + k0 + sc];
    *(uint4*)&Ws[sr][sc] = *(const uint4*)&Wcat[(size_t)(col0+sr)*DMODEL + k0 + sc];
    __syncthreads();

    bf16x8 af[2], bfr[2];
    #pragma unroll
    for (int mi=0; mi<2; ++mi) {
      const bf16* p = &Xs[wr + mi*16 + lr][kl];
      bf16x4 lo = *(const bf16x4*)p;
      bf16x4 hi = *(const bf16x4*)(p + 16);
      #pragma unroll
      for (int j=0;j<4;++j){ af[mi][j]=lo[j]; af[mi][j+4]=hi[j]; }
    }
    #pragma unroll
    for (int ni=0; ni<2; ++ni) {
      const bf16* p = &Ws[wc + ni*16 + lr][kl];
      bf16x4 lo = *(const bf16x4*)p;
      bf16x4 hi = *(const bf16x4*)(p + 16);
      #pragma unroll
      for (int j=0;j<4;++j){ bfr[ni][j]=lo[j]; bfr[ni][j+4]=hi[j]; }
    }
    #pragma unroll
    for (int mi=0; mi<2; ++mi)
      #pragma unroll
      for (int ni=0; ni<2; ++ni)
        acc[mi][ni] = __builtin_amdgcn_mfma_f32_16x16x32_bf16(af[mi], bfr[ni], acc[mi][ni], 0, 0, 0);
    __syncthreads();
  }

  const float* bias = (wsel==0) ? bq : ((wsel==1) ? bk : bv);
  bf16* Out = (wsel==0) ? Qo : ((wsel==1) ? Ko : Vo);

  #pragma unroll
  for (int ni=0; ni<2; ++ni) {
    const int co = coln + wc + ni*16 + lr;   // 0..1023
    const float bias_v = bias[co];
    const int h  = co >> 6;
    const int dh = co & 63;
    #pragma unroll
    for (int mi=0; mi<2; ++mi) {
      #pragma unroll
      for (int p=0; p<4; ++p) {
        const int gr = row0 + wr + mi*16 + ((lane>>4)<<2) + p;  // row in [0,4096)
        const int s_ = gr >> 2;
        const int b_ = gr & 3;
        const float val = acc[mi][ni][p] + bias_v;
        Out[((size_t)(b_*NHEAD + h)*S_LEN + s_)*DHEAD + dh] = (bf16)val;
      }
    }
  }
}

// ---------------- attention (VALU flash-style, fixed-shift softmax) ----------------
// Q/K/V: [B][H][S][DH] bf16; mask: [B][S] fp32; out: [S][B][D] fp32
#define TK 64
__global__ __launch_bounds__(256) void attn_kernel(
    const bf16* __restrict__ Q, const bf16* __restrict__ K, const bf16* __restrict__ V,
    const float* __restrict__ mask, float* __restrict__ out)
{
  __shared__ float Ks[TK][DHEAD];   // 16 KB
  __shared__ float Vs[TK][DHEAD];   // 16 KB
  __shared__ float Ms[TK];

  const int bh  = blockIdx.x;            // 0..63
  const int b_  = bh >> 4;
  const int h   = bh & 15;
  const int tid = threadIdx.x;
  const int rloc = tid >> 2;             // query row within chunk, 0..63
  const int dp   = (tid & 3) << 4;       // d-offset: 0,16,32,48
  const int qrow = blockIdx.y * 64 + rloc;  // s index

  // load q (16 floats), fold in 1/sqrt(DH)
  float q[16];
  {
    const bf16* qp = Q + ((size_t)bh*S_LEN + qrow)*DHEAD + dp;
    bf16x8 q0 = *(const bf16x8*)qp;
    bf16x8 q1 = *(const bf16x8*)(qp + 8);
    #pragma unroll
    for (int j=0;j<8;++j){ q[j]=(float)q0[j]*0.125f; q[8+j]=(float)q1[j]*0.125f; }
  }

  float ctx[16];
  #pragma unroll
  for (int j=0;j<16;++j) ctx[j]=0.f;
  float lsum = 0.f;

  const bf16* Kb = K + (size_t)bh*S_LEN*DHEAD;
  const bf16* Vb = V + (size_t)bh*S_LEN*DHEAD;
  const float* mb = mask + (size_t)b_*S_LEN;

  const int ssr = tid >> 2;              // staging row
  const int ssc = (tid & 3) << 4;        // staging col (16 elems)

  for (int t0 = 0; t0 < S_LEN; t0 += TK) {
    __syncthreads();   // protect LDS from previous tile's readers
    {
      const bf16* kp = Kb + (size_t)(t0+ssr)*DHEAD + ssc;
      bf16x8 k0 = *(const bf16x8*)kp;
      bf16x8 k1 = *(const bf16x8*)(kp+8);
      const bf16* vp = Vb + (size_t)(t0+ssr)*DHEAD + ssc;
      bf16x8 v0 = *(const bf16x8*)vp;
      bf16x8 v1 = *(const bf16x8*)(vp+8);
      #pragma unroll
      for (int j=0;j<8;++j){
        Ks[ssr][ssc+j]   = (float)k0[j];
        Ks[ssr][ssc+8+j] = (float)k1[j];
        Vs[ssr][ssc+j]   = (float)v0[j];
        Vs[ssr][ssc+8+j] = (float)v1[j];
      }
      if (tid < TK) Ms[tid] = mb[t0 + tid];
    }
    __syncthreads();

    for (int tt = 0; tt < TK; ++tt) {
      const float4* kr = (const float4*)&Ks[tt][dp];
      float4 k0 = kr[0], k1 = kr[1], k2 = kr[2], k3 = kr[3];
      float dot = q[0]*k0.x + q[1]*k0.y + q[2]*k0.z + q[3]*k0.w
                + q[4]*k1.x + q[5]*k1.y + q[6]*k1.z + q[7]*k1.w
                + q[8]*k2.x + q[9]*k2.y + q[10]*k2.z + q[11]*k2.w
                + q[12]*k3.x + q[13]*k3.y + q[14]*k3.z + q[15]*k3.w;
      dot += __shfl_xor(dot, 1);
      dot += __shfl_xor(dot, 2);
      const float p = __expf(dot + Ms[tt]);   // mask=-1e4 -> exp underflows to 0
      lsum += p;
      const float4* vr = (const float4*)&Vs[tt][dp];
      float4 v0 = vr[0], v1 = vr[1], v2 = vr[2], v3 = vr[3];
      ctx[0]+=p*v0.x; ctx[1]+=p*v0.y; ctx[2]+=p*v0.z; ctx[3]+=p*v0.w;
      ctx[4]+=p*v1.x; ctx[5]+=p*v1.y; ctx[6]+=p*v1.z; ctx[7]+=p*v1.w;
      ctx[8]+=p*v2.x; ctx[9]+=p*v2.y; ctx[10]+=p*v2.z; ctx[11]+=p*v2.w;
      ctx[12]+=p*v3.x; ctx[13]+=p*v3.y; ctx[14]+=p*v3.z; ctx[15]+=p*v3.w;
    }
  }

  const float inv = 1.f / lsum;
  float* op = out + ((size_t)qrow*BATCH + b_)*DMODEL + h*DHEAD + dp;
  #pragma unroll
  for (int j=0;j<4;++j) {
    float4 o; o.x=ctx[4*j]*inv; o.y=ctx[4*j+1]*inv; o.z=ctx[4*j+2]*inv; o.w=ctx[4*j+3]*inv;
    ((float4*)op)[j] = o;
  }
}

// ---------------- launch ----------------
extern "C" void kernel_launch(void* const* d_in, const int* in_sizes, int n_in,
                              void* d_out, int out_size, void* d_ws, size_t ws_size,
                              hipStream_t stream) {
  const float* hs   = (const float*)d_in[0];
  const float* mask = (const float*)d_in[1];
  const float* Wq   = (const float*)d_in[2];
  const float* bq   = (const float*)d_in[3];
  const float* Wk   = (const float*)d_in[4];
  const float* bk   = (const float*)d_in[5];
  const float* Wv   = (const float*)d_in[6];
  const float* bv   = (const float*)d_in[7];
  float* out = (float*)d_out;

  char* ws = (char*)d_ws;
  bf16* Xb = (bf16*)ws;                               //  8 MB: [4096][1024]
  bf16* Wb = Xb + (size_t)NROWS*DMODEL;               //  6 MB: [3][1024][1024]
  bf16* Qw = Wb + (size_t)3*DMODEL*DMODEL;            //  8 MB: [B][H][S][DH]
  bf16* Kw = Qw + (size_t)NROWS*DMODEL;               //  8 MB
  bf16* Vw = Kw + (size_t)NROWS*DMODEL;               //  8 MB

  cvt_f32_bf16<<<2048, 256, 0, stream>>>(hs, Xb, NROWS*DMODEL/8);
  cvt_f32_bf16<<<512, 256, 0, stream>>>(Wq, Wb,                         DMODEL*DMODEL/8);
  cvt_f32_bf16<<<512, 256, 0, stream>>>(Wk, Wb + (size_t)DMODEL*DMODEL, DMODEL*DMODEL/8);
  cvt_f32_bf16<<<512, 256, 0, stream>>>(Wv, Wb + (size_t)2*DMODEL*DMODEL, DMODEL*DMODEL/8);

  qkv_gemm<<<dim3(NROWS/BM, 3*DMODEL/BN), 256, 0, stream>>>(Xb, Wb, bq, bk, bv, Qw, Kw, Vw);

  attn_kernel<<<dim3(BATCH*NHEAD, S_LEN/64), 256, 0, stream>>>(Qw, Kw, Vw, mask, out);
}

// Round 2
// 133.594 us; speedup vs baseline: 3.5532x; 3.5532x over previous
//
#include <hip/hip_runtime.h>
#include <hip/hip_bf16.h>

#define S_LEN  1024
#define BATCH  4
#define DMODEL 1024
#define NHEAD  16
#define DHEAD  64
#define NROWS  (S_LEN*BATCH)   // 4096

typedef __bf16 bf16;
typedef __bf16 bf16x4 __attribute__((ext_vector_type(4)));
typedef __bf16 bf16x8 __attribute__((ext_vector_type(8)));
typedef float  f32x4  __attribute__((ext_vector_type(4)));

// ---------------- fp32 -> bf16 convert ----------------
__global__ __launch_bounds__(256) void cvt_f32_bf16(const float* __restrict__ src,
                                                    bf16* __restrict__ dst, int n8) {
  int i = blockIdx.x * 256 + threadIdx.x;
  if (i >= n8) return;
  const float4* s4 = (const float4*)src;
  float4 a = s4[2*i], b = s4[2*i+1];
  bf16x8 o;
  o[0]=(bf16)a.x; o[1]=(bf16)a.y; o[2]=(bf16)a.z; o[3]=(bf16)a.w;
  o[4]=(bf16)b.x; o[5]=(bf16)b.y; o[6]=(bf16)b.z; o[7]=(bf16)b.w;
  ((bf16x8*)dst)[i] = o;
}

// ---------------- fused QKV GEMM (bf16 MFMA) ----------------
#define BM 64
#define BN 64
#define BK 32
#define LDK 40   // padded LDS leading dim (bf16 elems)

__global__ __launch_bounds__(256) void qkv_gemm(
    const bf16* __restrict__ X, const bf16* __restrict__ Wcat,
    const float* __restrict__ bq, const float* __restrict__ bk, const float* __restrict__ bv,
    bf16* __restrict__ Qo, bf16* __restrict__ Ko, bf16* __restrict__ Vo)
{
  __shared__ bf16 Xs[BM][LDK];
  __shared__ bf16 Ws[BN][LDK];

  const int tid  = threadIdx.x;
  const int row0 = blockIdx.x * BM;
  const int col0 = blockIdx.y * BN;
  const int wsel = col0 >> 10;
  const int coln = col0 & 1023;

  const int sr = tid >> 2;
  const int sc = (tid & 3) << 3;

  const int wv   = tid >> 6;
  const int lane = tid & 63;
  const int wr   = (wv >> 1) << 5;
  const int wc   = (wv & 1) << 5;
  const int lr   = lane & 15;
  const int kl   = (lane >> 4) << 2;

  f32x4 acc[2][2];
  #pragma unroll
  for (int mi=0; mi<2; ++mi)
    #pragma unroll
    for (int ni=0; ni<2; ++ni)
      acc[mi][ni] = (f32x4){0.f,0.f,0.f,0.f};

  for (int k0 = 0; k0 < DMODEL; k0 += BK) {
    *(uint4*)&Xs[sr][sc] = *(const uint4*)&X[(size_t)(row0+sr)*DMODEL + k0 + sc];
    *(uint4*)&Ws[sr][sc] = *(const uint4*)&Wcat[(size_t)(col0+sr)*DMODEL + k0 + sc];
    __syncthreads();

    bf16x8 af[2], bfr[2];
    #pragma unroll
    for (int mi=0; mi<2; ++mi) {
      const bf16* p = &Xs[wr + mi*16 + lr][kl];
      bf16x4 lo = *(const bf16x4*)p;
      bf16x4 hi = *(const bf16x4*)(p + 16);
      #pragma unroll
      for (int j=0;j<4;++j){ af[mi][j]=lo[j]; af[mi][j+4]=hi[j]; }
    }
    #pragma unroll
    for (int ni=0; ni<2; ++ni) {
      const bf16* p = &Ws[wc + ni*16 + lr][kl];
      bf16x4 lo = *(const bf16x4*)p;
      bf16x4 hi = *(const bf16x4*)(p + 16);
      #pragma unroll
      for (int j=0;j<4;++j){ bfr[ni][j]=lo[j]; bfr[ni][j+4]=hi[j]; }
    }
    #pragma unroll
    for (int mi=0; mi<2; ++mi)
      #pragma unroll
      for (int ni=0; ni<2; ++ni)
        acc[mi][ni] = __builtin_amdgcn_mfma_f32_16x16x32_bf16(af[mi], bfr[ni], acc[mi][ni], 0, 0, 0);
    __syncthreads();
  }

  const float* bias = (wsel==0) ? bq : ((wsel==1) ? bk : bv);
  bf16* Out = (wsel==0) ? Qo : ((wsel==1) ? Ko : Vo);

  #pragma unroll
  for (int ni=0; ni<2; ++ni) {
    const int co = coln + wc + ni*16 + lr;
    const float bias_v = bias[co];
    const int h  = co >> 6;
    const int dh = co & 63;
    #pragma unroll
    for (int mi=0; mi<2; ++mi) {
      #pragma unroll
      for (int p=0; p<4; ++p) {
        const int gr = row0 + wr + mi*16 + ((lane>>4)<<2) + p;
        const int s_ = gr >> 2;
        const int b_ = gr & 3;
        const float val = acc[mi][ni][p] + bias_v;
        Out[((size_t)(b_*NHEAD + h)*S_LEN + s_)*DHEAD + dh] = (bf16)val;
      }
    }
  }
}

// ---------------- MFMA flash attention ----------------
// Q/K/V: [B][H][S][DH] bf16; mask: [B][S] fp32; out: [S][B][D] fp32
// Block: 4 waves, one (b,h), 64 q-rows (16 per wave). KV tiles of 64.
#define LPAD 72   // padded row stride in bf16 (144 B): fragment reads <=2-way bank conflict

__global__ __launch_bounds__(256) void attn_mfma(
    const bf16* __restrict__ Q, const bf16* __restrict__ K, const bf16* __restrict__ V,
    const float* __restrict__ mask, float* __restrict__ out)
{
  __shared__ __align__(16) bf16 Qs[64][LPAD];      // 9216 B
  __shared__ __align__(16) bf16 Ks[64][LPAD];      // 9216 B
  __shared__ __align__(16) bf16 Vt[64][LPAD];      // 9216 B (V transposed: Vt[d][t])
  __shared__ __align__(16) bf16 Pw[4][16][LPAD];   // 9216 B (per-wave P tile)
  __shared__ float Ms[64];

  const int bh   = blockIdx.x;           // 0..63
  const int b_   = bh >> 4;
  const int h    = bh & 15;
  const int tid  = threadIdx.x;
  const int wv   = tid >> 6;
  const int lane = tid & 63;
  const int lg   = lane >> 4;            // lane group 0..3
  const int lr   = lane & 15;            // lane remainder
  const int q0   = blockIdx.y * 64;

  const bf16* Qb = Q + ((size_t)bh*S_LEN + q0)*DHEAD;
  const bf16* Kb = K + (size_t)bh*S_LEN*DHEAD;
  const bf16* Vb = V + (size_t)bh*S_LEN*DHEAD;
  const float* mb = mask + (size_t)b_*S_LEN;

  // ---- stage Q tile (64x64), then hoist this wave's A-fragments to regs ----
  {
    const int r = tid >> 2, c = (tid & 3) << 4;
    const bf16x8* src = (const bf16x8*)&Qb[(size_t)r*DHEAD + c];
    *(bf16x8*)&Qs[r][c]   = src[0];
    *(bf16x8*)&Qs[r][c+8] = src[1];
  }
  __syncthreads();
  bf16x8 qa0 = *(const bf16x8*)&Qs[wv*16 + lr][lg*8];
  bf16x8 qa1 = *(const bf16x8*)&Qs[wv*16 + lr][32 + lg*8];

  f32x4 ctx[4];
  #pragma unroll
  for (int nt=0; nt<4; ++nt) ctx[nt] = (f32x4){0.f,0.f,0.f,0.f};
  float lsum[4] = {0.f,0.f,0.f,0.f};     // per accumulator reg (q-row lg*4+p)

  const int vr = tid & 63, vc = (tid >> 6) << 4;   // V transpose staging map

  for (int t0 = 0; t0 < S_LEN; t0 += 64) {
    __syncthreads();   // previous tile fully consumed
    // stage K (row-major) — 32 B per thread, coalesced
    {
      const int r = tid >> 2, c = (tid & 3) << 4;
      const bf16x8* src = (const bf16x8*)&Kb[(size_t)(t0+r)*DHEAD + c];
      *(bf16x8*)&Ks[r][c]   = src[0];
      *(bf16x8*)&Ks[r][c+8] = src[1];
    }
    // stage V transposed: thread reads 16 bf16 of row vr, scatters to Vt[c][vr]
    {
      const bf16x8* src = (const bf16x8*)&Vb[(size_t)(t0+vr)*DHEAD + vc];
      bf16x8 v0 = src[0], v1 = src[1];
      #pragma unroll
      for (int i=0;i<8;++i){ Vt[vc+i][vr] = v0[i]; Vt[vc+8+i][vr] = v1[i]; }
    }
    if (tid < 64) Ms[tid] = mb[t0 + tid];
    __syncthreads();

    // ---- QK^T: S[q][t], 4 col-tiles x 2 k-steps ----
    f32x4 sacc[4];
    #pragma unroll
    for (int nt=0; nt<4; ++nt) {
      sacc[nt] = (f32x4){0.f,0.f,0.f,0.f};
      bf16x8 kb0 = *(const bf16x8*)&Ks[nt*16 + lr][lg*8];
      bf16x8 kb1 = *(const bf16x8*)&Ks[nt*16 + lr][32 + lg*8];
      sacc[nt] = __builtin_amdgcn_mfma_f32_16x16x32_bf16(qa0, kb0, sacc[nt], 0,0,0);
      sacc[nt] = __builtin_amdgcn_mfma_f32_16x16x32_bf16(qa1, kb1, sacc[nt], 0,0,0);
    }

    // ---- softmax (no running max: scores bounded, mask underflows to 0) ----
    #pragma unroll
    for (int nt=0; nt<4; ++nt) {
      const float mval = Ms[nt*16 + lr];
      #pragma unroll
      for (int p=0; p<4; ++p) {
        const float pr = __expf(fmaf(sacc[nt][p], 0.125f, mval));
        lsum[p] += pr;
        Pw[wv][lg*4 + p][nt*16 + lr] = (bf16)pr;   // D-layout write
      }
    }

    // ---- PV: ctx[q][d] += P[q][t] * V[t][d]  (B-frag from transposed Vt) ----
    {
      bf16x8 pa0 = *(const bf16x8*)&Pw[wv][lr][lg*8];
      bf16x8 pa1 = *(const bf16x8*)&Pw[wv][lr][32 + lg*8];
      #pragma unroll
      for (int nt=0; nt<4; ++nt) {
        bf16x8 vb0 = *(const bf16x8*)&Vt[nt*16 + lr][lg*8];
        bf16x8 vb1 = *(const bf16x8*)&Vt[nt*16 + lr][32 + lg*8];
        ctx[nt] = __builtin_amdgcn_mfma_f32_16x16x32_bf16(pa0, vb0, ctx[nt], 0,0,0);
        ctx[nt] = __builtin_amdgcn_mfma_f32_16x16x32_bf16(pa1, vb1, ctx[nt], 0,0,0);
      }
    }
  }

  // ---- reduce lsum across the 16 columns (lanes sharing lg) ----
  #pragma unroll
  for (int p=0; p<4; ++p) {
    float s = lsum[p];
    s += __shfl_xor(s, 1); s += __shfl_xor(s, 2);
    s += __shfl_xor(s, 4); s += __shfl_xor(s, 8);
    lsum[p] = s;
  }

  // ---- write out: out[s][b][h*64 + d] ----
  #pragma unroll
  for (int p=0; p<4; ++p) {
    const float inv = 1.f / lsum[p];
    const int qg = q0 + wv*16 + lg*4 + p;
    float* op = out + ((size_t)qg*BATCH + b_)*DMODEL + h*DHEAD;
    #pragma unroll
    for (int nt=0; nt<4; ++nt) op[nt*16 + lr] = ctx[nt][p] * inv;
  }
}

// ---------------- launch ----------------
extern "C" void kernel_launch(void* const* d_in, const int* in_sizes, int n_in,
                              void* d_out, int out_size, void* d_ws, size_t ws_size,
                              hipStream_t stream) {
  const float* hs   = (const float*)d_in[0];
  const float* mask = (const float*)d_in[1];
  const float* Wq   = (const float*)d_in[2];
  const float* bq   = (const float*)d_in[3];
  const float* Wk   = (const float*)d_in[4];
  const float* bk   = (const float*)d_in[5];
  const float* Wv   = (const float*)d_in[6];
  const float* bv   = (const float*)d_in[7];
  float* out = (float*)d_out;

  char* ws = (char*)d_ws;
  bf16* Xb = (bf16*)ws;
  bf16* Wb = Xb + (size_t)NROWS*DMODEL;
  bf16* Qw = Wb + (size_t)3*DMODEL*DMODEL;
  bf16* Kw = Qw + (size_t)NROWS*DMODEL;
  bf16* Vw = Kw + (size_t)NROWS*DMODEL;

  cvt_f32_bf16<<<2048, 256, 0, stream>>>(hs, Xb, NROWS*DMODEL/8);
  cvt_f32_bf16<<<512, 256, 0, stream>>>(Wq, Wb,                           DMODEL*DMODEL/8);
  cvt_f32_bf16<<<512, 256, 0, stream>>>(Wk, Wb + (size_t)DMODEL*DMODEL,   DMODEL*DMODEL/8);
  cvt_f32_bf16<<<512, 256, 0, stream>>>(Wv, Wb + (size_t)2*DMODEL*DMODEL, DMODEL*DMODEL/8);

  qkv_gemm<<<dim3(NROWS/BM, 3*DMODEL/BN), 256, 0, stream>>>(Xb, Wb, bq, bk, bv, Qw, Kw, Vw);

  attn_mfma<<<dim3(BATCH*NHEAD, S_LEN/64), 256, 0, stream>>>(Qw, Kw, Vw, mask, out);
}

// Round 3
// 87.889 us; speedup vs baseline: 5.4010x; 1.5200x over previous
//
#include <hip/hip_runtime.h>
#include <hip/hip_bf16.h>

#define S_LEN  1024
#define BATCH  4
#define DMODEL 1024
#define NHEAD  16
#define DHEAD  64
#define NROWS  (S_LEN*BATCH)   // 4096

typedef __bf16 bf16;
typedef __bf16 bf16x4 __attribute__((ext_vector_type(4)));
typedef __bf16 bf16x8 __attribute__((ext_vector_type(8)));
typedef float  f32x4  __attribute__((ext_vector_type(4)));

#define AS1 __attribute__((address_space(1)))
#define AS3 __attribute__((address_space(3)))

__device__ __forceinline__ void gload16(const bf16* g, bf16* l) {
  __builtin_amdgcn_global_load_lds((const AS1 void*)g, (AS3 void*)l, 16, 0, 0);
}

// ---------------- fused fp32 -> bf16 convert (hs + 3 weights, one launch) ----------------
__global__ __launch_bounds__(256) void cvt_all(
    const float* __restrict__ hs, const float* __restrict__ wq,
    const float* __restrict__ wk, const float* __restrict__ wv,
    bf16* __restrict__ Xb, bf16* __restrict__ Wb)
{
  const int b = blockIdx.x;
  const float* src; bf16* dst; int i;
  if (b < 2048)      { src = hs; dst = Xb;                           i = b*256        + threadIdx.x; }
  else if (b < 2560) { src = wq; dst = Wb;                           i = (b-2048)*256 + threadIdx.x; }
  else if (b < 3072) { src = wk; dst = Wb + (size_t)DMODEL*DMODEL;   i = (b-2560)*256 + threadIdx.x; }
  else               { src = wv; dst = Wb + (size_t)2*DMODEL*DMODEL; i = (b-3072)*256 + threadIdx.x; }
  const float4* s4 = (const float4*)src;
  float4 a = s4[2*i], c = s4[2*i+1];
  bf16x8 o;
  o[0]=(bf16)a.x; o[1]=(bf16)a.y; o[2]=(bf16)a.z; o[3]=(bf16)a.w;
  o[4]=(bf16)c.x; o[5]=(bf16)c.y; o[6]=(bf16)c.z; o[7]=(bf16)c.w;
  ((bf16x8*)dst)[i] = o;
}

// ---------------- fused QKV GEMM, m97 structure ----------------
// X: [4096][1024] bf16, Wcat: [3072][1024] bf16 (rows = out features)
// 128x128 tile, BK=32, 4 waves (2x2), 4x4 frags/wave, global_load_lds staging.
#define BM 128
#define BN 128
#define BK 32

__global__ __launch_bounds__(256) void qkv_gemm(
    const bf16* __restrict__ X, const bf16* __restrict__ Wcat,
    const float* __restrict__ bq, const float* __restrict__ bk, const float* __restrict__ bv,
    bf16* __restrict__ Qo, bf16* __restrict__ Ko, bf16* __restrict__ Vo)
{
  __shared__ __align__(16) bf16 As[BM*BK];   // 8 KB, linear [row][k], 64 B/row
  __shared__ __align__(16) bf16 Bs[BN*BK];   // 8 KB

  const int tid  = threadIdx.x;
  const int row0 = blockIdx.x * BM;
  const int col0 = blockIdx.y * BN;          // 0..2944; 1024%128==0 -> never straddles q/k/v
  const int wsel = col0 >> 10;
  const int coln = col0 & 1023;

  const int wv   = tid >> 6;
  const int lane = tid & 63;
  const int lg   = lane >> 4;                // 0..3
  const int lr   = lane & 15;
  const int wr   = (wv >> 1) << 6;           // wave row offset 0/64
  const int wc   = (wv & 1) << 6;            // wave col offset 0/64

  // staging: 512 chunks of 16B per tile; thread covers chunk tid and tid+256.
  // chunk c -> row c>>2, 16B-slot c&3.  LDS dest = wave-uniform base + lane*16 (HW rule).
  const int c0 = tid, c1 = tid + 256;
  const size_t gA0 = (size_t)(row0 + (c0>>2))*DMODEL + (size_t)((c0&3)<<3);
  const size_t gA1 = (size_t)(row0 + (c1>>2))*DMODEL + (size_t)((c1&3)<<3);
  const size_t gB0 = (size_t)(col0 + (c0>>2))*DMODEL + (size_t)((c0&3)<<3);
  const size_t gB1 = (size_t)(col0 + (c1>>2))*DMODEL + (size_t)((c1&3)<<3);
  const int wb = (tid >> 6) << 6;            // wave*64 chunks
  bf16* lA0 = As + (size_t)wb*8;
  bf16* lA1 = As + (size_t)(wb+256)*8;
  bf16* lB0 = Bs + (size_t)wb*8;
  bf16* lB1 = Bs + (size_t)(wb+256)*8;

  f32x4 acc[4][4];
  #pragma unroll
  for (int mi=0; mi<4; ++mi)
    #pragma unroll
    for (int ni=0; ni<4; ++ni)
      acc[mi][ni] = (f32x4){0.f,0.f,0.f,0.f};

  for (int k0 = 0; k0 < DMODEL; k0 += BK) {
    __syncthreads();                         // prev tile fully consumed
    gload16(X    + gA0 + k0, lA0);
    gload16(X    + gA1 + k0, lA1);
    gload16(Wcat + gB0 + k0, lB0);
    gload16(Wcat + gB1 + k0, lB1);
    __syncthreads();                         // drains vmcnt -> tile ready

    bf16x8 af[4], bfr[4];
    #pragma unroll
    for (int mi=0; mi<4; ++mi)
      af[mi] = *(const bf16x8*)&As[(wr + mi*16 + lr)*BK + lg*8];
    #pragma unroll
    for (int ni=0; ni<4; ++ni)
      bfr[ni] = *(const bf16x8*)&Bs[(wc + ni*16 + lr)*BK + lg*8];

    #pragma unroll
    for (int mi=0; mi<4; ++mi)
      #pragma unroll
      for (int ni=0; ni<4; ++ni)
        acc[mi][ni] = __builtin_amdgcn_mfma_f32_16x16x32_bf16(af[mi], bfr[ni], acc[mi][ni], 0, 0, 0);
  }

  const float* bias = (wsel==0) ? bq : ((wsel==1) ? bk : bv);
  bf16* Out = (wsel==0) ? Qo : ((wsel==1) ? Ko : Vo);

  #pragma unroll
  for (int ni=0; ni<4; ++ni) {
    const int co = coln + wc + ni*16 + lr;   // 0..1023
    const float bias_v = bias[co];
    const int h  = co >> 6;
    const int dh = co & 63;
    #pragma unroll
    for (int mi=0; mi<4; ++mi) {
      #pragma unroll
      for (int p=0; p<4; ++p) {
        const int gr = row0 + wr + mi*16 + lg*4 + p;   // D layout: row=(lane>>4)*4+reg
        const int s_ = gr >> 2;
        const int b_ = gr & 3;
        Out[((size_t)(b_*NHEAD + h)*S_LEN + s_)*DHEAD + dh] = (bf16)(acc[mi][ni][p] + bias_v);
      }
    }
  }
}

// ---------------- MFMA flash attention (unchanged from round 2) ----------------
#define LPAD 72

__global__ __launch_bounds__(256) void attn_mfma(
    const bf16* __restrict__ Q, const bf16* __restrict__ K, const bf16* __restrict__ V,
    const float* __restrict__ mask, float* __restrict__ out)
{
  __shared__ __align__(16) bf16 Qs[64][LPAD];
  __shared__ __align__(16) bf16 Ks[64][LPAD];
  __shared__ __align__(16) bf16 Vt[64][LPAD];
  __shared__ __align__(16) bf16 Pw[4][16][LPAD];
  __shared__ float Ms[64];

  const int bh   = blockIdx.x;
  const int b_   = bh >> 4;
  const int h    = bh & 15;
  const int tid  = threadIdx.x;
  const int wv   = tid >> 6;
  const int lane = tid & 63;
  const int lg   = lane >> 4;
  const int lr   = lane & 15;
  const int q0   = blockIdx.y * 64;

  const bf16* Qb = Q + ((size_t)bh*S_LEN + q0)*DHEAD;
  const bf16* Kb = K + (size_t)bh*S_LEN*DHEAD;
  const bf16* Vb = V + (size_t)bh*S_LEN*DHEAD;
  const float* mb = mask + (size_t)b_*S_LEN;

  {
    const int r = tid >> 2, c = (tid & 3) << 4;
    const bf16x8* src = (const bf16x8*)&Qb[(size_t)r*DHEAD + c];
    *(bf16x8*)&Qs[r][c]   = src[0];
    *(bf16x8*)&Qs[r][c+8] = src[1];
  }
  __syncthreads();
  bf16x8 qa0 = *(const bf16x8*)&Qs[wv*16 + lr][lg*8];
  bf16x8 qa1 = *(const bf16x8*)&Qs[wv*16 + lr][32 + lg*8];

  f32x4 ctx[4];
  #pragma unroll
  for (int nt=0; nt<4; ++nt) ctx[nt] = (f32x4){0.f,0.f,0.f,0.f};
  float lsum[4] = {0.f,0.f,0.f,0.f};

  const int vr = tid & 63, vc = (tid >> 6) << 4;

  for (int t0 = 0; t0 < S_LEN; t0 += 64) {
    __syncthreads();
    {
      const int r = tid >> 2, c = (tid & 3) << 4;
      const bf16x8* src = (const bf16x8*)&Kb[(size_t)(t0+r)*DHEAD + c];
      *(bf16x8*)&Ks[r][c]   = src[0];
      *(bf16x8*)&Ks[r][c+8] = src[1];
    }
    {
      const bf16x8* src = (const bf16x8*)&Vb[(size_t)(t0+vr)*DHEAD + vc];
      bf16x8 v0 = src[0], v1 = src[1];
      #pragma unroll
      for (int i=0;i<8;++i){ Vt[vc+i][vr] = v0[i]; Vt[vc+8+i][vr] = v1[i]; }
    }
    if (tid < 64) Ms[tid] = mb[t0 + tid];
    __syncthreads();

    f32x4 sacc[4];
    #pragma unroll
    for (int nt=0; nt<4; ++nt) {
      sacc[nt] = (f32x4){0.f,0.f,0.f,0.f};
      bf16x8 kb0 = *(const bf16x8*)&Ks[nt*16 + lr][lg*8];
      bf16x8 kb1 = *(const bf16x8*)&Ks[nt*16 + lr][32 + lg*8];
      sacc[nt] = __builtin_amdgcn_mfma_f32_16x16x32_bf16(qa0, kb0, sacc[nt], 0,0,0);
      sacc[nt] = __builtin_amdgcn_mfma_f32_16x16x32_bf16(qa1, kb1, sacc[nt], 0,0,0);
    }

    #pragma unroll
    for (int nt=0; nt<4; ++nt) {
      const float mval = Ms[nt*16 + lr];
      #pragma unroll
      for (int p=0; p<4; ++p) {
        const float pr = __expf(fmaf(sacc[nt][p], 0.125f, mval));
        lsum[p] += pr;
        Pw[wv][lg*4 + p][nt*16 + lr] = (bf16)pr;
      }
    }

    {
      bf16x8 pa0 = *(const bf16x8*)&Pw[wv][lr][lg*8];
      bf16x8 pa1 = *(const bf16x8*)&Pw[wv][lr][32 + lg*8];
      #pragma unroll
      for (int nt=0; nt<4; ++nt) {
        bf16x8 vb0 = *(const bf16x8*)&Vt[nt*16 + lr][lg*8];
        bf16x8 vb1 = *(const bf16x8*)&Vt[nt*16 + lr][32 + lg*8];
        ctx[nt] = __builtin_amdgcn_mfma_f32_16x16x32_bf16(pa0, vb0, ctx[nt], 0,0,0);
        ctx[nt] = __builtin_amdgcn_mfma_f32_16x16x32_bf16(pa1, vb1, ctx[nt], 0,0,0);
      }
    }
  }

  #pragma unroll
  for (int p=0; p<4; ++p) {
    float s = lsum[p];
    s += __shfl_xor(s, 1); s += __shfl_xor(s, 2);
    s += __shfl_xor(s, 4); s += __shfl_xor(s, 8);
    lsum[p] = s;
  }

  #pragma unroll
  for (int p=0; p<4; ++p) {
    const float inv = 1.f / lsum[p];
    const int qg = q0 + wv*16 + lg*4 + p;
    float* op = out + ((size_t)qg*BATCH + b_)*DMODEL + h*DHEAD;
    #pragma unroll
    for (int nt=0; nt<4; ++nt) op[nt*16 + lr] = ctx[nt][p] * inv;
  }
}

// ---------------- launch ----------------
extern "C" void kernel_launch(void* const* d_in, const int* in_sizes, int n_in,
                              void* d_out, int out_size, void* d_ws, size_t ws_size,
                              hipStream_t stream) {
  const float* hs   = (const float*)d_in[0];
  const float* mask = (const float*)d_in[1];
  const float* Wq   = (const float*)d_in[2];
  const float* bq   = (const float*)d_in[3];
  const float* Wk   = (const float*)d_in[4];
  const float* bk   = (const float*)d_in[5];
  const float* Wv   = (const float*)d_in[6];
  const float* bv   = (const float*)d_in[7];
  float* out = (float*)d_out;

  char* ws = (char*)d_ws;
  bf16* Xb = (bf16*)ws;
  bf16* Wb = Xb + (size_t)NROWS*DMODEL;
  bf16* Qw = Wb + (size_t)3*DMODEL*DMODEL;
  bf16* Kw = Qw + (size_t)NROWS*DMODEL;
  bf16* Vw = Kw + (size_t)NROWS*DMODEL;

  cvt_all<<<3584, 256, 0, stream>>>(hs, Wq, Wk, Wv, Xb, Wb);

  qkv_gemm<<<dim3(NROWS/BM, 3*DMODEL/BN), 256, 0, stream>>>(Xb, Wb, bq, bk, bv, Qw, Kw, Vw);

  attn_mfma<<<dim3(BATCH*NHEAD, S_LEN/64), 256, 0, stream>>>(Qw, Kw, Vw, mask, out);
}

// Round 4
// 83.365 us; speedup vs baseline: 5.6941x; 1.0543x over previous
//
#include <hip/hip_runtime.h>
#include <hip/hip_bf16.h>

#define S_LEN  1024
#define BATCH  4
#define DMODEL 1024
#define NHEAD  16
#define DHEAD  64
#define NROWS  (S_LEN*BATCH)   // 4096

typedef __bf16 bf16;
typedef __bf16 bf16x4 __attribute__((ext_vector_type(4)));
typedef __bf16 bf16x8 __attribute__((ext_vector_type(8)));
typedef float  f32x4  __attribute__((ext_vector_type(4)));

#define AS1 __attribute__((address_space(1)))
#define AS3 __attribute__((address_space(3)))

#define LOG2E   1.4426950408889634f
#define QSCALE  0.18033688011112042f   // 0.125 * log2(e)

__device__ __forceinline__ void gload16(const bf16* g, bf16* l) {
  __builtin_amdgcn_global_load_lds((const AS1 void*)g, (AS3 void*)l, 16, 0, 0);
}

__device__ __forceinline__ float fast_exp2(float x) {
#if __has_builtin(__builtin_amdgcn_exp2f)
  return __builtin_amdgcn_exp2f(x);
#else
  return exp2f(x);
#endif
}

// ---------------- fused fp32 -> bf16 convert (hs + 3 weights, one launch) ----------------
__global__ __launch_bounds__(256) void cvt_all(
    const float* __restrict__ hs, const float* __restrict__ wq,
    const float* __restrict__ wk, const float* __restrict__ wv,
    bf16* __restrict__ Xb, bf16* __restrict__ Wb)
{
  const int b = blockIdx.x;
  const float* src; bf16* dst; int i;
  if (b < 2048)      { src = hs; dst = Xb;                           i = b*256        + threadIdx.x; }
  else if (b < 2560) { src = wq; dst = Wb;                           i = (b-2048)*256 + threadIdx.x; }
  else if (b < 3072) { src = wk; dst = Wb + (size_t)DMODEL*DMODEL;   i = (b-2560)*256 + threadIdx.x; }
  else               { src = wv; dst = Wb + (size_t)2*DMODEL*DMODEL; i = (b-3072)*256 + threadIdx.x; }
  const float4* s4 = (const float4*)src;
  float4 a = s4[2*i], c = s4[2*i+1];
  bf16x8 o;
  o[0]=(bf16)a.x; o[1]=(bf16)a.y; o[2]=(bf16)a.z; o[3]=(bf16)a.w;
  o[4]=(bf16)c.x; o[5]=(bf16)c.y; o[6]=(bf16)c.z; o[7]=(bf16)c.w;
  ((bf16x8*)dst)[i] = o;
}

// ---------------- fused QKV GEMM, m97 structure ----------------
#define BM 128
#define BN 128
#define BK 32

__global__ __launch_bounds__(256) void qkv_gemm(
    const bf16* __restrict__ X, const bf16* __restrict__ Wcat,
    const float* __restrict__ bq, const float* __restrict__ bk, const float* __restrict__ bv,
    bf16* __restrict__ Qo, bf16* __restrict__ Ko, bf16* __restrict__ Vo)
{
  __shared__ __align__(16) bf16 As[BM*BK];   // 8 KB linear
  __shared__ __align__(16) bf16 Bs[BN*BK];   // 8 KB

  const int tid  = threadIdx.x;
  const int row0 = blockIdx.x * BM;
  const int col0 = blockIdx.y * BN;
  const int wsel = col0 >> 10;
  const int coln = col0 & 1023;

  const int wv   = tid >> 6;
  const int lane = tid & 63;
  const int lg   = lane >> 4;
  const int lr   = lane & 15;
  const int wr   = (wv >> 1) << 6;
  const int wc   = (wv & 1) << 6;

  const int c0 = tid, c1 = tid + 256;
  const size_t gA0 = (size_t)(row0 + (c0>>2))*DMODEL + (size_t)((c0&3)<<3);
  const size_t gA1 = (size_t)(row0 + (c1>>2))*DMODEL + (size_t)((c1&3)<<3);
  const size_t gB0 = (size_t)(col0 + (c0>>2))*DMODEL + (size_t)((c0&3)<<3);
  const size_t gB1 = (size_t)(col0 + (c1>>2))*DMODEL + (size_t)((c1&3)<<3);
  const int wb = (tid >> 6) << 6;
  bf16* lA0 = As + (size_t)wb*8;
  bf16* lA1 = As + (size_t)(wb+256)*8;
  bf16* lB0 = Bs + (size_t)wb*8;
  bf16* lB1 = Bs + (size_t)(wb+256)*8;

  f32x4 acc[4][4];
  #pragma unroll
  for (int mi=0; mi<4; ++mi)
    #pragma unroll
    for (int ni=0; ni<4; ++ni)
      acc[mi][ni] = (f32x4){0.f,0.f,0.f,0.f};

  for (int k0 = 0; k0 < DMODEL; k0 += BK) {
    __syncthreads();
    gload16(X    + gA0 + k0, lA0);
    gload16(X    + gA1 + k0, lA1);
    gload16(Wcat + gB0 + k0, lB0);
    gload16(Wcat + gB1 + k0, lB1);
    __syncthreads();

    bf16x8 af[4], bfr[4];
    #pragma unroll
    for (int mi=0; mi<4; ++mi)
      af[mi] = *(const bf16x8*)&As[(wr + mi*16 + lr)*BK + lg*8];
    #pragma unroll
    for (int ni=0; ni<4; ++ni)
      bfr[ni] = *(const bf16x8*)&Bs[(wc + ni*16 + lr)*BK + lg*8];

    #pragma unroll
    for (int mi=0; mi<4; ++mi)
      #pragma unroll
      for (int ni=0; ni<4; ++ni)
        acc[mi][ni] = __builtin_amdgcn_mfma_f32_16x16x32_bf16(af[mi], bfr[ni], acc[mi][ni], 0, 0, 0);
  }

  const float* bias = (wsel==0) ? bq : ((wsel==1) ? bk : bv);
  bf16* Out = (wsel==0) ? Qo : ((wsel==1) ? Ko : Vo);
  const float oscale = (wsel==0) ? QSCALE : 1.0f;   // fold 0.125*log2e into Q

  #pragma unroll
  for (int ni=0; ni<4; ++ni) {
    const int co = coln + wc + ni*16 + lr;
    const float bias_v = bias[co];
    const int h  = co >> 6;
    const int dh = co & 63;
    #pragma unroll
    for (int mi=0; mi<4; ++mi) {
      #pragma unroll
      for (int p=0; p<4; ++p) {
        const int gr = row0 + wr + mi*16 + lg*4 + p;
        const int s_ = gr >> 2;
        const int b_ = gr & 3;
        Out[((size_t)(b_*NHEAD + h)*S_LEN + s_)*DHEAD + dh] = (bf16)((acc[mi][ni][p] + bias_v) * oscale);
      }
    }
  }
}

// ---------------- MFMA flash attention, async reg-staged K/V ----------------
// Q pre-scaled by 0.125*log2e; mask folded to log2-domain; softmax = add + exp2.
#define LPAD 72

__global__ __launch_bounds__(256, 4) void attn_mfma(
    const bf16* __restrict__ Q, const bf16* __restrict__ K, const bf16* __restrict__ V,
    const float* __restrict__ mask, float* __restrict__ out)
{
  __shared__ __align__(16) bf16 Ks[64*LPAD];       // 9216 B
  __shared__ __align__(16) bf16 Vt[64*LPAD];       // 9216 B (transposed)
  __shared__ __align__(16) bf16 Pw[4][16][LPAD];   // 9216 B
  __shared__ bf16 Msk[S_LEN];                      // 2048 B, mask * log2e

  const int bh   = blockIdx.x;
  const int b_   = bh >> 4;
  const int h    = bh & 15;
  const int tid  = threadIdx.x;
  const int wv   = tid >> 6;
  const int lane = tid & 63;
  const int lg   = lane >> 4;
  const int lr   = lane & 15;
  const int q0   = blockIdx.y * 64;

  // ---- stage mask row (once): 1024 entries * log2e -> bf16 LDS ----
  {
    const float4 m4 = *(const float4*)&mask[(size_t)b_*S_LEN + tid*4];
    bf16x4 mm;
    mm[0]=(bf16)(m4.x*LOG2E); mm[1]=(bf16)(m4.y*LOG2E);
    mm[2]=(bf16)(m4.z*LOG2E); mm[3]=(bf16)(m4.w*LOG2E);
    *(bf16x4*)&Msk[tid*4] = mm;
  }

  // ---- Q fragments straight from global (no LDS) ----
  const bf16* Qb = Q + ((size_t)bh*S_LEN + q0 + wv*16 + lr)*DHEAD;
  const bf16x8 qa0 = *(const bf16x8*)&Qb[lg*8];
  const bf16x8 qa1 = *(const bf16x8*)&Qb[32 + lg*8];

  const bf16* Kb = K + (size_t)bh*S_LEN*DHEAD;
  const bf16* Vb = V + (size_t)bh*S_LEN*DHEAD;

  const int kr = tid >> 2, kc = (tid & 3) << 4;    // K staging map
  const int vr = tid & 63, vc = (tid >> 6) << 4;   // V staging map

  // ---- prologue: tile 0 -> regs -> LDS ----
  bf16x8 kreg0 = *(const bf16x8*)&Kb[(size_t)kr*DHEAD + kc];
  bf16x8 kreg1 = *(const bf16x8*)&Kb[(size_t)kr*DHEAD + kc + 8];
  bf16x8 vreg0 = *(const bf16x8*)&Vb[(size_t)vr*DHEAD + vc];
  bf16x8 vreg1 = *(const bf16x8*)&Vb[(size_t)vr*DHEAD + vc + 8];
  *(bf16x8*)&Ks[kr*LPAD + kc]     = kreg0;
  *(bf16x8*)&Ks[kr*LPAD + kc + 8] = kreg1;
  #pragma unroll
  for (int i=0;i<8;++i){ Vt[(vc+i)*LPAD + vr] = vreg0[i]; Vt[(vc+8+i)*LPAD + vr] = vreg1[i]; }
  __syncthreads();

  f32x4 ctx[4];
  #pragma unroll
  for (int nt=0; nt<4; ++nt) ctx[nt] = (f32x4){0.f,0.f,0.f,0.f};
  float lsum[4] = {0.f,0.f,0.f,0.f};

  for (int t = 0; t < 16; ++t) {
    // ---- issue next tile's global loads early (latency hides under compute) ----
    if (t < 15) {
      const size_t nb = (size_t)(t+1)*64;
      kreg0 = *(const bf16x8*)&Kb[(nb+kr)*DHEAD + kc];
      kreg1 = *(const bf16x8*)&Kb[(nb+kr)*DHEAD + kc + 8];
      vreg0 = *(const bf16x8*)&Vb[(nb+vr)*DHEAD + vc];
      vreg1 = *(const bf16x8*)&Vb[(nb+vr)*DHEAD + vc + 8];
    }

    // ---- QK^T ----
    f32x4 sacc[4];
    __builtin_amdgcn_s_setprio(1);
    #pragma unroll
    for (int nt=0; nt<4; ++nt) {
      sacc[nt] = (f32x4){0.f,0.f,0.f,0.f};
      bf16x8 kb0 = *(const bf16x8*)&Ks[(nt*16 + lr)*LPAD + lg*8];
      bf16x8 kb1 = *(const bf16x8*)&Ks[(nt*16 + lr)*LPAD + 32 + lg*8];
      sacc[nt] = __builtin_amdgcn_mfma_f32_16x16x32_bf16(qa0, kb0, sacc[nt], 0,0,0);
      sacc[nt] = __builtin_amdgcn_mfma_f32_16x16x32_bf16(qa1, kb1, sacc[nt], 0,0,0);
    }
    __builtin_amdgcn_s_setprio(0);

    // ---- softmax: p = exp2(s + m) (Q pre-scaled; no running max needed) ----
    const int tb = t*64;
    #pragma unroll
    for (int nt=0; nt<4; ++nt) {
      const float mval = (float)Msk[tb + nt*16 + lr];
      #pragma unroll
      for (int p=0; p<4; ++p) {
        const float pr = fast_exp2(sacc[nt][p] + mval);
        lsum[p] += pr;
        Pw[wv][lg*4 + p][nt*16 + lr] = (bf16)pr;
      }
    }

    // ---- PV ----
    {
      bf16x8 pa0 = *(const bf16x8*)&Pw[wv][lr][lg*8];
      bf16x8 pa1 = *(const bf16x8*)&Pw[wv][lr][32 + lg*8];
      __builtin_amdgcn_s_setprio(1);
      #pragma unroll
      for (int nt=0; nt<4; ++nt) {
        bf16x8 vb0 = *(const bf16x8*)&Vt[(nt*16 + lr)*LPAD + lg*8];
        bf16x8 vb1 = *(const bf16x8*)&Vt[(nt*16 + lr)*LPAD + 32 + lg*8];
        ctx[nt] = __builtin_amdgcn_mfma_f32_16x16x32_bf16(pa0, vb0, ctx[nt], 0,0,0);
        ctx[nt] = __builtin_amdgcn_mfma_f32_16x16x32_bf16(pa1, vb1, ctx[nt], 0,0,0);
      }
      __builtin_amdgcn_s_setprio(0);
    }

    __syncthreads();                 // all waves done reading Ks/Vt
    if (t < 15) {
      *(bf16x8*)&Ks[kr*LPAD + kc]     = kreg0;
      *(bf16x8*)&Ks[kr*LPAD + kc + 8] = kreg1;
      #pragma unroll
      for (int i=0;i<8;++i){ Vt[(vc+i)*LPAD + vr] = vreg0[i]; Vt[(vc+8+i)*LPAD + vr] = vreg1[i]; }
      __syncthreads();               // new tile visible
    }
  }

  // ---- lsum reduce across the 16 columns ----
  #pragma unroll
  for (int p=0; p<4; ++p) {
    float s = lsum[p];
    s += __shfl_xor(s, 1); s += __shfl_xor(s, 2);
    s += __shfl_xor(s, 4); s += __shfl_xor(s, 8);
    lsum[p] = s;
  }

  // ---- write out: out[s][b][h*64 + d] ----
  #pragma unroll
  for (int p=0; p<4; ++p) {
    const float inv = 1.f / lsum[p];
    const int qg = q0 + wv*16 + lg*4 + p;
    float* op = out + ((size_t)qg*BATCH + b_)*DMODEL + h*DHEAD;
    #pragma unroll
    for (int nt=0; nt<4; ++nt) op[nt*16 + lr] = ctx[nt][p] * inv;
  }
}

// ---------------- launch ----------------
extern "C" void kernel_launch(void* const* d_in, const int* in_sizes, int n_in,
                              void* d_out, int out_size, void* d_ws, size_t ws_size,
                              hipStream_t stream) {
  const float* hs   = (const float*)d_in[0];
  const float* mask = (const float*)d_in[1];
  const float* Wq   = (const float*)d_in[2];
  const float* bq   = (const float*)d_in[3];
  const float* Wk   = (const float*)d_in[4];
  const float* bk   = (const float*)d_in[5];
  const float* Wv   = (const float*)d_in[6];
  const float* bv   = (const float*)d_in[7];
  float* out = (float*)d_out;

  char* ws = (char*)d_ws;
  bf16* Xb = (bf16*)ws;
  bf16* Wb = Xb + (size_t)NROWS*DMODEL;
  bf16* Qw = Wb + (size_t)3*DMODEL*DMODEL;
  bf16* Kw = Qw + (size_t)NROWS*DMODEL;
  bf16* Vw = Kw + (size_t)NROWS*DMODEL;

  cvt_all<<<3584, 256, 0, stream>>>(hs, Wq, Wk, Wv, Xb, Wb);

  qkv_gemm<<<dim3(NROWS/BM, 3*DMODEL/BN), 256, 0, stream>>>(Xb, Wb, bq, bk, bv, Qw, Kw, Vw);

  attn_mfma<<<dim3(BATCH*NHEAD, S_LEN/64), 256, 0, stream>>>(Qw, Kw, Vw, mask, out);
}

// Round 5
// 78.566 us; speedup vs baseline: 6.0419x; 1.0611x over previous
//
#include <hip/hip_runtime.h>
#include <hip/hip_bf16.h>

#define S_LEN  1024
#define BATCH  4
#define DMODEL 1024
#define NHEAD  16
#define DHEAD  64
#define NROWS  (S_LEN*BATCH)   // 4096

typedef __bf16 bf16;
typedef __bf16 bf16x4 __attribute__((ext_vector_type(4)));
typedef __bf16 bf16x8 __attribute__((ext_vector_type(8)));
typedef float  f32x4  __attribute__((ext_vector_type(4)));

#define AS1 __attribute__((address_space(1)))
#define AS3 __attribute__((address_space(3)))

#define LOG2E   1.4426950408889634f
#define QSCALE  0.18033688011112042f   // 0.125 * log2(e)

__device__ __forceinline__ void gload16(const bf16* g, bf16* l) {
  __builtin_amdgcn_global_load_lds((const AS1 void*)g, (AS3 void*)l, 16, 0, 0);
}

__device__ __forceinline__ float fast_exp2(float x) {
#if __has_builtin(__builtin_amdgcn_exp2f)
  return __builtin_amdgcn_exp2f(x);
#else
  return exp2f(x);
#endif
}

// ---------------- fused fp32 -> bf16 convert (hs + 3 weights, one launch) ----------------
__global__ __launch_bounds__(256) void cvt_all(
    const float* __restrict__ hs, const float* __restrict__ wq,
    const float* __restrict__ wk, const float* __restrict__ wv,
    bf16* __restrict__ Xb, bf16* __restrict__ Wb)
{
  const int b = blockIdx.x;
  const float* src; bf16* dst; int i;
  if (b < 2048)      { src = hs; dst = Xb;                           i = b*256        + threadIdx.x; }
  else if (b < 2560) { src = wq; dst = Wb;                           i = (b-2048)*256 + threadIdx.x; }
  else if (b < 3072) { src = wk; dst = Wb + (size_t)DMODEL*DMODEL;   i = (b-2560)*256 + threadIdx.x; }
  else               { src = wv; dst = Wb + (size_t)2*DMODEL*DMODEL; i = (b-3072)*256 + threadIdx.x; }
  const float4* s4 = (const float4*)src;
  float4 a = s4[2*i], c = s4[2*i+1];
  bf16x8 o;
  o[0]=(bf16)a.x; o[1]=(bf16)a.y; o[2]=(bf16)a.z; o[3]=(bf16)a.w;
  o[4]=(bf16)c.x; o[5]=(bf16)c.y; o[6]=(bf16)c.z; o[7]=(bf16)c.w;
  ((bf16x8*)dst)[i] = o;
}

// ---------------- fused QKV GEMM, m97 structure ----------------
#define BM 128
#define BN 128
#define BK 32

__global__ __launch_bounds__(256) void qkv_gemm(
    const bf16* __restrict__ X, const bf16* __restrict__ Wcat,
    const float* __restrict__ bq, const float* __restrict__ bk, const float* __restrict__ bv,
    bf16* __restrict__ Qo, bf16* __restrict__ Ko, bf16* __restrict__ Vo)
{
  __shared__ __align__(16) bf16 As[BM*BK];   // 8 KB linear
  __shared__ __align__(16) bf16 Bs[BN*BK];   // 8 KB

  const int tid  = threadIdx.x;
  const int row0 = blockIdx.x * BM;
  const int col0 = blockIdx.y * BN;
  const int wsel = col0 >> 10;
  const int coln = col0 & 1023;

  const int wv   = tid >> 6;
  const int lane = tid & 63;
  const int lg   = lane >> 4;
  const int lr   = lane & 15;
  const int wr   = (wv >> 1) << 6;
  const int wc   = (wv & 1) << 6;

  const int c0 = tid, c1 = tid + 256;
  const size_t gA0 = (size_t)(row0 + (c0>>2))*DMODEL + (size_t)((c0&3)<<3);
  const size_t gA1 = (size_t)(row0 + (c1>>2))*DMODEL + (size_t)((c1&3)<<3);
  const size_t gB0 = (size_t)(col0 + (c0>>2))*DMODEL + (size_t)((c0&3)<<3);
  const size_t gB1 = (size_t)(col0 + (c1>>2))*DMODEL + (size_t)((c1&3)<<3);
  const int wb = (tid >> 6) << 6;
  bf16* lA0 = As + (size_t)wb*8;
  bf16* lA1 = As + (size_t)(wb+256)*8;
  bf16* lB0 = Bs + (size_t)wb*8;
  bf16* lB1 = Bs + (size_t)(wb+256)*8;

  f32x4 acc[4][4];
  #pragma unroll
  for (int mi=0; mi<4; ++mi)
    #pragma unroll
    for (int ni=0; ni<4; ++ni)
      acc[mi][ni] = (f32x4){0.f,0.f,0.f,0.f};

  for (int k0 = 0; k0 < DMODEL; k0 += BK) {
    __syncthreads();
    gload16(X    + gA0 + k0, lA0);
    gload16(X    + gA1 + k0, lA1);
    gload16(Wcat + gB0 + k0, lB0);
    gload16(Wcat + gB1 + k0, lB1);
    __syncthreads();

    bf16x8 af[4], bfr[4];
    #pragma unroll
    for (int mi=0; mi<4; ++mi)
      af[mi] = *(const bf16x8*)&As[(wr + mi*16 + lr)*BK + lg*8];
    #pragma unroll
    for (int ni=0; ni<4; ++ni)
      bfr[ni] = *(const bf16x8*)&Bs[(wc + ni*16 + lr)*BK + lg*8];

    #pragma unroll
    for (int mi=0; mi<4; ++mi)
      #pragma unroll
      for (int ni=0; ni<4; ++ni)
        acc[mi][ni] = __builtin_amdgcn_mfma_f32_16x16x32_bf16(af[mi], bfr[ni], acc[mi][ni], 0, 0, 0);
  }

  const float* bias = (wsel==0) ? bq : ((wsel==1) ? bk : bv);
  bf16* Out = (wsel==0) ? Qo : ((wsel==1) ? Ko : Vo);
  const float oscale = (wsel==0) ? QSCALE : 1.0f;   // fold 0.125*log2e into Q

  #pragma unroll
  for (int ni=0; ni<4; ++ni) {
    const int co = coln + wc + ni*16 + lr;
    const float bias_v = bias[co];
    const int h  = co >> 6;
    const int dh = co & 63;
    #pragma unroll
    for (int mi=0; mi<4; ++mi) {
      #pragma unroll
      for (int p=0; p<4; ++p) {
        const int gr = row0 + wr + mi*16 + lg*4 + p;
        const int s_ = gr >> 2;
        const int b_ = gr & 3;
        Out[((size_t)(b_*NHEAD + h)*S_LEN + s_)*DHEAD + dh] = (bf16)((acc[mi][ni][p] + bias_v) * oscale);
      }
    }
  }
}

// ---------------- MFMA flash attention: 8 waves, 128 q-rows, dbuf K/V, 1 barrier/tile ----
#define LPAD 72
#define QBLK 128

__global__ __launch_bounds__(512, 4) void attn_mfma(
    const bf16* __restrict__ Q, const bf16* __restrict__ K, const bf16* __restrict__ V,
    const float* __restrict__ mask, float* __restrict__ out)
{
  __shared__ __align__(16) bf16 KsBuf[2][64*LPAD];   // 18432 B
  __shared__ __align__(16) bf16 VtBuf[2][64*LPAD];   // 18432 B (transposed Vt[d][t])
  __shared__ __align__(16) bf16 Pw[8][16][LPAD];     // 18432 B
  __shared__ bf16 Msk[S_LEN];                        //  2048 B

  const int bh   = blockIdx.x;
  const int b_   = bh >> 4;
  const int h    = bh & 15;
  const int tid  = threadIdx.x;
  const int wv   = tid >> 6;             // 0..7
  const int lane = tid & 63;
  const int lg   = lane >> 4;
  const int lr   = lane & 15;
  const int q0   = blockIdx.y * QBLK;

  // ---- stage mask row (once): 1024 entries * log2e -> bf16 LDS ----
  if (tid < 256) {
    const float4 m4 = *(const float4*)&mask[(size_t)b_*S_LEN + tid*4];
    bf16x4 mm;
    mm[0]=(bf16)(m4.x*LOG2E); mm[1]=(bf16)(m4.y*LOG2E);
    mm[2]=(bf16)(m4.z*LOG2E); mm[3]=(bf16)(m4.w*LOG2E);
    *(bf16x4*)&Msk[tid*4] = mm;
  }

  // ---- Q fragments straight from global (pre-scaled by QSCALE in gemm) ----
  const bf16* Qb = Q + ((size_t)bh*S_LEN + q0 + wv*16 + lr)*DHEAD;
  const bf16x8 qa0 = *(const bf16x8*)&Qb[lg*8];
  const bf16x8 qa1 = *(const bf16x8*)&Qb[32 + lg*8];

  const bf16* Kb = K + (size_t)bh*S_LEN*DHEAD;
  const bf16* Vb = V + (size_t)bh*S_LEN*DHEAD;

  // staging maps (512 threads, one K-tile row-chunk + one V-column-chunk each)
  const int kr = tid >> 3, kc = (tid & 7) << 3;     // K: row, col8  (coalesced b128)
  const int vr = tid & 63, vc = (tid >> 6) << 3;    // V: row=lane (bank-free scatter)

  // ---- prologue: tile 0 ----
  bf16x8 kreg = *(const bf16x8*)&Kb[(size_t)kr*DHEAD + kc];
  bf16x8 vreg = *(const bf16x8*)&Vb[(size_t)vr*DHEAD + vc];
  *(bf16x8*)&KsBuf[0][kr*LPAD + kc] = kreg;
  #pragma unroll
  for (int i=0;i<8;++i) VtBuf[0][(vc+i)*LPAD + vr] = vreg[i];
  __syncthreads();

  f32x4 ctx[4];
  #pragma unroll
  for (int nt=0; nt<4; ++nt) ctx[nt] = (f32x4){0.f,0.f,0.f,0.f};
  float lsum[4] = {0.f,0.f,0.f,0.f};

  for (int t = 0; t < 16; ++t) {
    const bf16* Kc = KsBuf[t & 1];
    const bf16* Vc = VtBuf[t & 1];

    // issue next tile's global loads early (latency hides under compute)
    if (t < 15) {
      const size_t nb = (size_t)(t+1)*64;
      kreg = *(const bf16x8*)&Kb[(nb+kr)*DHEAD + kc];
      vreg = *(const bf16x8*)&Vb[(nb+vr)*DHEAD + vc];
    }

    // ---- QK^T ----
    f32x4 sacc[4];
    __builtin_amdgcn_s_setprio(1);
    #pragma unroll
    for (int nt=0; nt<4; ++nt) {
      sacc[nt] = (f32x4){0.f,0.f,0.f,0.f};
      bf16x8 kb0 = *(const bf16x8*)&Kc[(nt*16 + lr)*LPAD + lg*8];
      bf16x8 kb1 = *(const bf16x8*)&Kc[(nt*16 + lr)*LPAD + 32 + lg*8];
      sacc[nt] = __builtin_amdgcn_mfma_f32_16x16x32_bf16(qa0, kb0, sacc[nt], 0,0,0);
      sacc[nt] = __builtin_amdgcn_mfma_f32_16x16x32_bf16(qa1, kb1, sacc[nt], 0,0,0);
    }
    __builtin_amdgcn_s_setprio(0);

    // ---- softmax: p = exp2(s + m) ----
    const int tb = t*64;
    #pragma unroll
    for (int nt=0; nt<4; ++nt) {
      const float mval = (float)Msk[tb + nt*16 + lr];
      #pragma unroll
      for (int p=0; p<4; ++p) {
        const float pr = fast_exp2(sacc[nt][p] + mval);
        lsum[p] += pr;
        Pw[wv][lg*4 + p][nt*16 + lr] = (bf16)pr;
      }
    }

    // ---- PV ----
    {
      bf16x8 pa0 = *(const bf16x8*)&Pw[wv][lr][lg*8];
      bf16x8 pa1 = *(const bf16x8*)&Pw[wv][lr][32 + lg*8];
      __builtin_amdgcn_s_setprio(1);
      #pragma unroll
      for (int nt=0; nt<4; ++nt) {
        bf16x8 vb0 = *(const bf16x8*)&Vc[(nt*16 + lr)*LPAD + lg*8];
        bf16x8 vb1 = *(const bf16x8*)&Vc[(nt*16 + lr)*LPAD + 32 + lg*8];
        ctx[nt] = __builtin_amdgcn_mfma_f32_16x16x32_bf16(pa0, vb0, ctx[nt], 0,0,0);
        ctx[nt] = __builtin_amdgcn_mfma_f32_16x16x32_bf16(pa1, vb1, ctx[nt], 0,0,0);
      }
      __builtin_amdgcn_s_setprio(0);
    }

    // ---- stage next tile into the other buffer (no reader until after barrier) ----
    if (t < 15) {
      bf16* Kn = (bf16*)KsBuf[(t+1) & 1];
      bf16* Vn = (bf16*)VtBuf[(t+1) & 1];
      *(bf16x8*)&Kn[kr*LPAD + kc] = kreg;
      #pragma unroll
      for (int i=0;i<8;++i) Vn[(vc+i)*LPAD + vr] = vreg[i];
    }
    __syncthreads();
  }

  // ---- lsum reduce across the 16 columns ----
  #pragma unroll
  for (int p=0; p<4; ++p) {
    float s = lsum[p];
    s += __shfl_xor(s, 1); s += __shfl_xor(s, 2);
    s += __shfl_xor(s, 4); s += __shfl_xor(s, 8);
    lsum[p] = s;
  }

  // ---- write out: out[s][b][h*64 + d] ----
  #pragma unroll
  for (int p=0; p<4; ++p) {
    const float inv = 1.f / lsum[p];
    const int qg = q0 + wv*16 + lg*4 + p;
    float* op = out + ((size_t)qg*BATCH + b_)*DMODEL + h*DHEAD;
    #pragma unroll
    for (int nt=0; nt<4; ++nt) op[nt*16 + lr] = ctx[nt][p] * inv;
  }
}

// ---------------- launch ----------------
extern "C" void kernel_launch(void* const* d_in, const int* in_sizes, int n_in,
                              void* d_out, int out_size, void* d_ws, size_t ws_size,
                              hipStream_t stream) {
  const float* hs   = (const float*)d_in[0];
  const float* mask = (const float*)d_in[1];
  const float* Wq   = (const float*)d_in[2];
  const float* bq   = (const float*)d_in[3];
  const float* Wk   = (const float*)d_in[4];
  const float* bk   = (const float*)d_in[5];
  const float* Wv   = (const float*)d_in[6];
  const float* bv   = (const float*)d_in[7];
  float* out = (float*)d_out;

  char* ws = (char*)d_ws;
  bf16* Xb = (bf16*)ws;
  bf16* Wb = Xb + (size_t)NROWS*DMODEL;
  bf16* Qw = Wb + (size_t)3*DMODEL*DMODEL;
  bf16* Kw = Qw + (size_t)NROWS*DMODEL;
  bf16* Vw = Kw + (size_t)NROWS*DMODEL;

  cvt_all<<<3584, 256, 0, stream>>>(hs, Wq, Wk, Wv, Xb, Wb);

  qkv_gemm<<<dim3(NROWS/BM, 3*DMODEL/BN), 256, 0, stream>>>(Xb, Wb, bq, bk, bv, Qw, Kw, Vw);

  attn_mfma<<<dim3(BATCH*NHEAD, S_LEN/QBLK), 512, 0, stream>>>(Qw, Kw, Vw, mask, out);
}